// Round 7
// baseline (848.265 us; speedup 1.0000x reference)
//
#include <hip/hip_runtime.h>
#include <hip/hip_fp16.h>

#define H 128
#define EPS 1e-5f
#define BCAP 6144  // max edges per 256-node bucket (mean 4096)
#define SLB 2048   // agg blocks per slice

typedef __attribute__((ext_vector_type(8))) _Float16 half8;
typedef __attribute__((ext_vector_type(4))) float f32x4;

__device__ inline __half2 u2h2(unsigned u) { return __builtin_bit_cast(__half2, u); }
__device__ inline unsigned h22u(__half2 h) { return __builtin_bit_cast(unsigned, h); }

// ---------------- x f32 -> f16, slice-major layout ----------------
// hxs layout: slice s (16 feats) of node nd at byte (s*N + nd)*32
__global__ void convert_kernel(const float* __restrict__ x, char* __restrict__ hxs, int N) {
    int tid = blockIdx.x * 256 + threadIdx.x;
    int twoN = N * 2;
    if (tid >= twoN * 8) return;
    int s = tid / twoN;
    int rem = tid - s * twoN;
    int nd = rem >> 1, hh = rem & 1;
    const float* xp = x + (size_t)nd * H + s * 16 + hh * 8;
    float4 a = *reinterpret_cast<const float4*>(xp);
    float4 b2 = *reinterpret_cast<const float4*>(xp + 4);
    unsigned p0 = h22u(__floats2half2_rn(a.x, a.y));
    unsigned p1 = h22u(__floats2half2_rn(a.z, a.w));
    unsigned p2 = h22u(__floats2half2_rn(b2.x, b2.y));
    unsigned p3 = h22u(__floats2half2_rn(b2.z, b2.w));
    *reinterpret_cast<uint4*>(hxs + (((size_t)s * N + nd) << 5) + hh * 16) =
        make_uint4(p0, p1, p2, p3);
}

// ---------------- CSR build: bucket histogram (bucket = dst>>8) ----------------
__global__ __launch_bounds__(256) void bhist_kernel(const int* __restrict__ dst,
                                                    int* __restrict__ ghist, int E, int NB) {
    __shared__ int hist[512];
    int t = threadIdx.x;
    for (int i = t; i < NB; i += 256) hist[i] = 0;
    __syncthreads();
    int base = blockIdx.x * 8192 + t;
#pragma unroll
    for (int k = 0; k < 32; ++k) {
        int e = base + k * 256;
        if (e < E) atomicAdd(&hist[dst[e] >> 8], 1);
    }
    __syncthreads();
    for (int i = t; i < NB; i += 256)
        if (hist[i]) atomicAdd(&ghist[i], hist[i]);
}

__global__ __launch_bounds__(512) void bscan_kernel(const int* __restrict__ ghist,
                                                    int* __restrict__ bucket_base,
                                                    int* __restrict__ cursor,
                                                    int* __restrict__ row_start,
                                                    int NB, int E, int N) {
    __shared__ int lds[512];
    int t = threadIdx.x;
    int v = (t < NB) ? ghist[t] : 0;
    lds[t] = v;
    __syncthreads();
    for (int off = 1; off < 512; off <<= 1) {
        int u = (t >= off) ? lds[t - off] : 0;
        __syncthreads();
        lds[t] += u;
        __syncthreads();
    }
    int excl = lds[t] - v;
    if (t < NB) {
        bucket_base[t] = excl;
        cursor[t] = excl;
    }
    if (t == 0) {
        bucket_base[NB] = E;
        row_start[N] = E;
    }
}

// ---------------- bucketize: group edges by bucket in LDS, flush coalesced ----------------
__global__ __launch_bounds__(1024) void bucketize_kernel(const int* __restrict__ src,
                                                         const int* __restrict__ dst,
                                                         const float* __restrict__ ew,
                                                         int* __restrict__ cursor,
                                                         int2* __restrict__ ee, int E, int NB) {
    __shared__ int hist[512];
    __shared__ int scn[512];
    __shared__ int gbase[512];
    __shared__ int2 stage[8192];
    int t = threadIdx.x;
    for (int i = t; i < NB; i += 1024) hist[i] = 0;
    __syncthreads();

    int e0 = blockIdx.x * 8192;
    int bb[8], rk[8], pk[8], wb[8];
#pragma unroll
    for (int k = 0; k < 8; ++k) {
        int e = e0 + t + k * 1024;
        if (e < E) {
            int s = src[e], d = dst[e];
            bb[k] = d >> 8;
            pk[k] = s | ((d & 255) << 17);
            wb[k] = __float_as_int(ew[e]);
            rk[k] = atomicAdd(&hist[bb[k]], 1);
        } else {
            bb[k] = -1;
        }
    }
    __syncthreads();
    if (t < 512) scn[t] = (t < NB) ? hist[t] : 0;
    __syncthreads();
    for (int off = 1; off < 512; off <<= 1) {
        int u = 0;
        if (t < 512 && t >= off) u = scn[t - off];
        __syncthreads();
        if (t < 512) scn[t] += u;
        __syncthreads();
    }
    for (int i = t; i < NB; i += 1024) {
        int c = hist[i];
        if (c > 0) gbase[i] = atomicAdd(&cursor[i], c);
    }
#pragma unroll
    for (int k = 0; k < 8; ++k) {
        if (bb[k] >= 0) {
            int start = scn[bb[k]] - hist[bb[k]];
            stage[start + rk[k]] = make_int2(pk[k], wb[k]);
        }
    }
    __syncthreads();
    int wv = t >> 6, ln = t & 63;
    for (int bk = wv; bk < NB; bk += 16) {
        int c = hist[bk];
        if (c == 0) continue;
        int s0 = scn[bk] - c;
        int gb = gbase[bk];
        for (int i = ln; i < c; i += 64) ee[gb + i] = stage[s0 + i];
    }
}

// ------ per-bucket counting sort + row_start + weight normalization -> 4B records ------
// rec = (src << 15) | (half_bits(wn) >> 1), wn = w / max(sum_w(dst),1)
__global__ __launch_bounds__(256) void bsort_kernel(const int2* __restrict__ ee,
                                                    const int* __restrict__ bucket_base,
                                                    int* __restrict__ row_start,
                                                    unsigned* __restrict__ ee4, int N) {
    __shared__ int cnts[256];
    __shared__ int scv[256];
    __shared__ int prefs[256];
    __shared__ int2 out[BCAP];
    int b = blockIdx.x;
    int base = bucket_base[b], endb = bucket_base[b + 1];
    int cnt = endb - base;
    int t = threadIdx.x;
    cnts[t] = 0;
    __syncthreads();
    for (int i = base + t; i < endb; i += 256) atomicAdd(&cnts[(ee[i].x >> 17) & 255], 1);
    __syncthreads();
    scv[t] = cnts[t];
    __syncthreads();
    for (int off = 1; off < 256; off <<= 1) {
        int u = (t >= off) ? scv[t - off] : 0;
        __syncthreads();
        scv[t] += u;
        __syncthreads();
    }
    int pref = scv[t] - cnts[t];  // exclusive
    prefs[t] = pref;
    int node = (b << 8) + t;
    if (node < N) row_start[node] = base + pref;
    __syncthreads();
    cnts[t] = 0;
    __syncthreads();
    for (int i = base + t; i < endb; i += 256) {
        int2 r = ee[i];
        int dl = (r.x >> 17) & 255;
        int rkk = atomicAdd(&cnts[dl], 1);
        int slot = prefs[dl] + rkk;
        if (slot < BCAP) out[slot] = make_int2(r.x & 0x1FFFF, r.y);
    }
    __syncthreads();
    // normalize this node's weights
    {
        int s0 = prefs[t], c = cnts[t];
        float sw = 0.f;
        for (int k = 0; k < c; ++k) sw += __int_as_float(out[s0 + k].y);
        sw = sw < 1.f ? 1.f : sw;
        float inv = 1.f / sw;
        for (int k = 0; k < c; ++k) {
            float w = __int_as_float(out[s0 + k].y) * inv;
            out[s0 + k].y = (int)(unsigned)__half_as_ushort(__float2half(w));
        }
    }
    __syncthreads();
    for (int i = t; i < cnt; i += 256)
        ee4[base + i] = ((unsigned)out[i].x << 15) | ((unsigned)out[i].y >> 1);
}

// ---------------- gather-aggregate, feature-sliced for L2 residency ----------------
// blockIdx&7 = slice s (lands on XCD s under round-robin dispatch); the slice's
// h (3.2 MB) fits the XCD's 4 MB L2. Wave: 4 nodes x (2-edge-parity x 8 col-pairs).
__global__ __launch_bounds__(256) void agg_kernel(const char* __restrict__ hxs,
                                                  const int* __restrict__ row_start,
                                                  const unsigned* __restrict__ ee4,
                                                  char* __restrict__ aggs, int N) {
    int s = blockIdx.x & 7;
    int cb = blockIdx.x >> 3;
    int t = threadIdx.x;
    int w = t >> 6, lane = t & 63;
    int g = lane >> 4;         // node sub (0..3)
    int eo = (lane >> 3) & 1;  // edge parity
    int c = lane & 7;          // column pair (h2)
    size_t sN = (size_t)s * N;
#pragma unroll
    for (int r = 0; r < 4; ++r) {
        int nd = (cb * 4 + r) * 16 + w * 4 + g;
        int rs = 0, re = 0;
        if (nd < N) {
            rs = row_start[nd];
            re = row_start[nd + 1];
        }
        __half2 acc = u2h2(0);
        int idx = rs + eo;
        while (__any(idx < re)) {
            bool act = idx < re;
            int ii = act ? idx : 0;
            unsigned rec = __builtin_nontemporal_load(ee4 + ii);
            rec = act ? rec : 0u;  // w=0 for inactive lanes -> zero contribution
            unsigned hw = (rec & 0x7FFFu) << 1;
            __half2 w2 = u2h2(hw | (hw << 16));
            unsigned srcv = rec >> 15;
            unsigned hv = *reinterpret_cast<const unsigned*>(hxs + ((sN + srcv) << 5) + c * 4);
            acc = __hfma2(u2h2(hv), w2, acc);
            idx += 2;
        }
        acc = __hadd2(acc, u2h2((unsigned)__shfl_xor((int)h22u(acc), 8)));
        if (eo == 0 && nd < N) {
            __builtin_nontemporal_store(
                h22u(acc), reinterpret_cast<unsigned*>(aggs + ((sN + nd) << 5) + c * 4));
        }
    }
}

// ---------------- MFMA dual-GEMM + bias + relu + layernorm (f16, sliced A) ----------------
__global__ __launch_bounds__(256, 2) void gemm_ln_mfma(
    const char* __restrict__ aggs, const char* __restrict__ hxs,
    const float* __restrict__ Wn, const float* __restrict__ Wr,
    const float* __restrict__ br, const float* __restrict__ g,
    const float* __restrict__ b, unsigned short* __restrict__ hout,
    float* __restrict__ outf, int final_layer, int N) {
    __shared__ half8 Bfl[4096];  // 64 KB

    int t = threadIdx.x;
    int w = t >> 6, lane = t & 63;
    int Mbase = blockIdx.x * 256;

#pragma unroll
    for (int it = 0; it < 16; ++it) {
        int f = it * 4 + w;
        int kt = f >> 3, nb = f & 7;
        int n = nb * 16 + (lane & 15);
        int kk = (kt & 3) * 32 + (lane >> 4) * 8;
        const float* wp = ((kt < 4) ? Wn : Wr) + (size_t)n * H + kk;
        float4 wa = *reinterpret_cast<const float4*>(wp);
        float4 wb = *reinterpret_cast<const float4*>(wp + 4);
        half8 sv;
        sv[0] = (_Float16)wa.x; sv[1] = (_Float16)wa.y;
        sv[2] = (_Float16)wa.z; sv[3] = (_Float16)wa.w;
        sv[4] = (_Float16)wb.x; sv[5] = (_Float16)wb.y;
        sv[6] = (_Float16)wb.z; sv[7] = (_Float16)wb.w;
        Bfl[f * 64 + lane] = sv;
    }
    __syncthreads();

    int lrow = lane & 15, lk = lane >> 4;
    int lk1 = lk & 1, lkh = lk >> 1;
    size_t rowb[4];
#pragma unroll
    for (int mf = 0; mf < 4; ++mf) {
        int r = Mbase + w * 64 + mf * 16 + lrow;
        r = r < N ? r : N - 1;
        rowb[mf] = (size_t)r << 5;  // r*32 bytes within a slice
    }

    f32x4 acc[4][8];
#pragma unroll
    for (int mf = 0; mf < 4; ++mf)
#pragma unroll
        for (int nb = 0; nb < 8; ++nb) acc[mf][nb] = (f32x4){0.f, 0.f, 0.f, 0.f};

#pragma unroll
    for (int kt = 0; kt < 8; ++kt) {
        const char* base = (kt < 4) ? aggs : hxs;
        // slice s2 = (kt&3)*2 + lkh ; 16B sub-block lk1 within the 32B slice-row
        size_t soff = (((size_t)((kt & 3) * 2 + lkh)) * (size_t)N << 5) + (size_t)lk1 * 16;
        half8 bf[8];
#pragma unroll
        for (int nb = 0; nb < 8; ++nb) bf[nb] = Bfl[(kt * 8 + nb) * 64 + lane];
#pragma unroll
        for (int mf = 0; mf < 4; ++mf) {
            half8 av = *reinterpret_cast<const half8*>(base + soff + rowb[mf]);
#pragma unroll
            for (int nb = 0; nb < 8; ++nb)
                acc[mf][nb] = __builtin_amdgcn_mfma_f32_16x16x32_f16(av, bf[nb], acc[mf][nb], 0, 0, 0);
        }
    }

    int col0 = lane & 15, rq = lane >> 4;
    float bias[8], gg[8], bbv[8];
#pragma unroll
    for (int nb = 0; nb < 8; ++nb) {
        int cc = col0 + nb * 16;
        bias[nb] = br[cc];
        gg[nb] = g[cc];
        bbv[nb] = b[cc];
    }
#pragma unroll
    for (int mf = 0; mf < 4; ++mf) {
#pragma unroll
        for (int reg = 0; reg < 4; ++reg) {
            float v[8];
            float sacc = 0.f, q = 0.f;
#pragma unroll
            for (int nb = 0; nb < 8; ++nb) {
                float u = acc[mf][nb][reg] + bias[nb];
                u = fmaxf(u, 0.f);
                v[nb] = u;
                sacc += u;
                q = fmaf(u, u, q);
            }
#pragma unroll
            for (int off = 1; off < 16; off <<= 1) {
                sacc += __shfl_xor(sacc, off);
                q += __shfl_xor(q, off);
            }
            float mu = sacc * (1.f / 128.f);
            float var = q * (1.f / 128.f) - mu * mu;
            float inv = rsqrtf(var + EPS);
            int grow = Mbase + w * 64 + mf * 16 + rq * 4 + reg;
            if (grow < N) {
                if (final_layer) {
#pragma unroll
                    for (int nb = 0; nb < 8; ++nb)
                        outf[(size_t)grow * H + col0 + nb * 16] = (v[nb] - mu) * inv * gg[nb] + bbv[nb];
                } else {
#pragma unroll
                    for (int nb = 0; nb < 8; ++nb)
                        hout[(((size_t)nb * N + grow) << 4) + col0] =
                            __half_as_ushort(__float2half((v[nb] - mu) * inv * gg[nb] + bbv[nb]));
                }
            }
        }
    }
}

static inline size_t alignup(size_t x) { return (x + 255) & ~(size_t)255; }

extern "C" void kernel_launch(void* const* d_in, const int* in_sizes, int n_in,
                              void* d_out, int out_size, void* d_ws, size_t ws_size,
                              hipStream_t stream) {
    const float* x  = (const float*)d_in[0];
    const int*   ei = (const int*)d_in[1];
    const float* ew = (const float*)d_in[2];
    const float* Wn = (const float*)d_in[3];
    const float* Wr = (const float*)d_in[4];
    const float* br = (const float*)d_in[5];
    const float* g  = (const float*)d_in[6];
    const float* bb = (const float*)d_in[7];
    float* out = (float*)d_out;

    int N = in_sizes[0] / H;
    int E = in_sizes[2];
    const int* src = ei;
    const int* dst = ei + E;
    int NB = (N + 255) >> 8;

    // ws layout (bytes)
    char* ws = (char*)d_ws;
    size_t off = 0;
    int* ghist = (int*)(ws + off);         off = alignup(off + sizeof(int) * 512);
    int* bucket_base = (int*)(ws + off);   off = alignup(off + sizeof(int) * 513);
    int* cursor = (int*)(ws + off);        off = alignup(off + sizeof(int) * 512);
    int* row_start = (int*)(ws + off);     off = alignup(off + sizeof(int) * ((size_t)N + 1));
    int2* ee = (int2*)(ws + off);          off = alignup(off + sizeof(int2) * (size_t)E);
    unsigned* ee4 = (unsigned*)(ws + off); off = alignup(off + sizeof(unsigned) * (size_t)E);
    char* aggs = ws + off;                 off = alignup(off + 2ull * N * H);
    char* hxs  = ws + off;                 off = alignup(off + 2ull * N * H);

    int eblocks = (E + 8191) / 8192;

    // CSR build via bucketed counting sort (+ weight normalization, 4B records)
    hipMemsetAsync(ghist, 0, sizeof(int) * 512, stream);
    bhist_kernel<<<eblocks, 256, 0, stream>>>(dst, ghist, E, NB);
    bscan_kernel<<<1, 512, 0, stream>>>(ghist, bucket_base, cursor, row_start, NB, E, N);
    bucketize_kernel<<<eblocks, 1024, 0, stream>>>(src, dst, ew, cursor, ee, E, NB);
    bsort_kernel<<<NB, 256, 0, stream>>>(ee, bucket_base, row_start, ee4, N);

    // x -> f16 sliced ping buffer
    int cthreads = N * 16;
    convert_kernel<<<(cthreads + 255) / 256, 256, 0, stream>>>(x, hxs, N);

    int gblocks = (N + 255) / 256;
    for (int l = 0; l < 3; ++l) {
        agg_kernel<<<8 * SLB, 256, 0, stream>>>(hxs, row_start, ee4, aggs, N);
        gemm_ln_mfma<<<gblocks, 256, 0, stream>>>(
            aggs, hxs,
            Wn + (size_t)l * H * H, Wr + (size_t)l * H * H, br + (size_t)l * H,
            g + (size_t)l * H, bb + (size_t)l * H,
            (unsigned short*)hxs, out, (l == 2) ? 1 : 0, N);
    }
}

// Round 8
// 540.093 us; speedup vs baseline: 1.5706x; 1.5706x over previous
//
#include <hip/hip_runtime.h>
#include <hip/hip_fp16.h>

#define H 128
#define EPS 1e-5f
#define BCAP 6144  // max edges per 256-node bucket (mean 4096)

typedef __attribute__((ext_vector_type(8))) _Float16 half8;
typedef __attribute__((ext_vector_type(4))) float f32x4;

__device__ inline __half2 u2h2(unsigned u) { return __builtin_bit_cast(__half2, u); }
__device__ inline unsigned h22u(__half2 h) { return __builtin_bit_cast(unsigned, h); }

// ---------------- x f32 -> f16, slice-major layout ----------------
// hxs layout: slice s (16 feats) of node nd at byte (s*N + nd)*32
__global__ void convert_kernel(const float* __restrict__ x, char* __restrict__ hxs, int N) {
    int tid = blockIdx.x * 256 + threadIdx.x;
    int twoN = N * 2;
    if (tid >= twoN * 8) return;
    int s = tid / twoN;
    int rem = tid - s * twoN;
    int nd = rem >> 1, hh = rem & 1;
    const float* xp = x + (size_t)nd * H + s * 16 + hh * 8;
    float4 a = *reinterpret_cast<const float4*>(xp);
    float4 b2 = *reinterpret_cast<const float4*>(xp + 4);
    unsigned p0 = h22u(__floats2half2_rn(a.x, a.y));
    unsigned p1 = h22u(__floats2half2_rn(a.z, a.w));
    unsigned p2 = h22u(__floats2half2_rn(b2.x, b2.y));
    unsigned p3 = h22u(__floats2half2_rn(b2.z, b2.w));
    *reinterpret_cast<uint4*>(hxs + (((size_t)s * N + nd) << 5) + hh * 16) =
        make_uint4(p0, p1, p2, p3);
}

// ---------------- CSR build: bucket histogram (bucket = dst>>8) ----------------
__global__ __launch_bounds__(256) void bhist_kernel(const int* __restrict__ dst,
                                                    int* __restrict__ ghist, int E, int NB) {
    __shared__ int hist[512];
    int t = threadIdx.x;
    for (int i = t; i < NB; i += 256) hist[i] = 0;
    __syncthreads();
    int base = blockIdx.x * 8192 + t;
#pragma unroll
    for (int k = 0; k < 32; ++k) {
        int e = base + k * 256;
        if (e < E) atomicAdd(&hist[dst[e] >> 8], 1);
    }
    __syncthreads();
    for (int i = t; i < NB; i += 256)
        if (hist[i]) atomicAdd(&ghist[i], hist[i]);
}

__global__ __launch_bounds__(512) void bscan_kernel(const int* __restrict__ ghist,
                                                    int* __restrict__ bucket_base,
                                                    int* __restrict__ cursor,
                                                    int* __restrict__ row_start,
                                                    int NB, int E, int N) {
    __shared__ int lds[512];
    int t = threadIdx.x;
    int v = (t < NB) ? ghist[t] : 0;
    lds[t] = v;
    __syncthreads();
    for (int off = 1; off < 512; off <<= 1) {
        int u = (t >= off) ? lds[t - off] : 0;
        __syncthreads();
        lds[t] += u;
        __syncthreads();
    }
    int excl = lds[t] - v;
    if (t < NB) {
        bucket_base[t] = excl;
        cursor[t] = excl;
    }
    if (t == 0) {
        bucket_base[NB] = E;
        row_start[N] = E;
    }
}

// ---------------- bucketize: group edges by bucket in LDS, flush coalesced ----------------
__global__ __launch_bounds__(1024) void bucketize_kernel(const int* __restrict__ src,
                                                         const int* __restrict__ dst,
                                                         const float* __restrict__ ew,
                                                         int* __restrict__ cursor,
                                                         int2* __restrict__ ee, int E, int NB) {
    __shared__ int hist[512];
    __shared__ int scn[512];
    __shared__ int gbase[512];
    __shared__ int2 stage[8192];
    int t = threadIdx.x;
    for (int i = t; i < NB; i += 1024) hist[i] = 0;
    __syncthreads();

    int e0 = blockIdx.x * 8192;
    int bb[8], rk[8], pk[8], wb[8];
#pragma unroll
    for (int k = 0; k < 8; ++k) {
        int e = e0 + t + k * 1024;
        if (e < E) {
            int s = src[e], d = dst[e];
            bb[k] = d >> 8;
            pk[k] = s | ((d & 255) << 17);
            wb[k] = __float_as_int(ew[e]);
            rk[k] = atomicAdd(&hist[bb[k]], 1);
        } else {
            bb[k] = -1;
        }
    }
    __syncthreads();
    if (t < 512) scn[t] = (t < NB) ? hist[t] : 0;
    __syncthreads();
    for (int off = 1; off < 512; off <<= 1) {
        int u = 0;
        if (t < 512 && t >= off) u = scn[t - off];
        __syncthreads();
        if (t < 512) scn[t] += u;
        __syncthreads();
    }
    for (int i = t; i < NB; i += 1024) {
        int c = hist[i];
        if (c > 0) gbase[i] = atomicAdd(&cursor[i], c);
    }
#pragma unroll
    for (int k = 0; k < 8; ++k) {
        if (bb[k] >= 0) {
            int start = scn[bb[k]] - hist[bb[k]];
            stage[start + rk[k]] = make_int2(pk[k], wb[k]);
        }
    }
    __syncthreads();
    int wv = t >> 6, ln = t & 63;
    for (int bk = wv; bk < NB; bk += 16) {
        int c = hist[bk];
        if (c == 0) continue;
        int s0 = scn[bk] - c;
        int gb = gbase[bk];
        for (int i = ln; i < c; i += 64) ee[gb + i] = stage[s0 + i];
    }
}

// ------ per-bucket counting sort + row_start + weight normalization -> 4B records ------
// rec = (src << 15) | (half_bits(wn) >> 1), wn = w / max(sum_w(dst),1)
__global__ __launch_bounds__(256) void bsort_kernel(const int2* __restrict__ ee,
                                                    const int* __restrict__ bucket_base,
                                                    int* __restrict__ row_start,
                                                    unsigned* __restrict__ ee4, int N) {
    __shared__ int cnts[256];
    __shared__ int scv[256];
    __shared__ int prefs[256];
    __shared__ int2 out[BCAP];
    int b = blockIdx.x;
    int base = bucket_base[b], endb = bucket_base[b + 1];
    int cnt = endb - base;
    int t = threadIdx.x;
    cnts[t] = 0;
    __syncthreads();
    for (int i = base + t; i < endb; i += 256) atomicAdd(&cnts[(ee[i].x >> 17) & 255], 1);
    __syncthreads();
    scv[t] = cnts[t];
    __syncthreads();
    for (int off = 1; off < 256; off <<= 1) {
        int u = (t >= off) ? scv[t - off] : 0;
        __syncthreads();
        scv[t] += u;
        __syncthreads();
    }
    int pref = scv[t] - cnts[t];  // exclusive
    prefs[t] = pref;
    int node = (b << 8) + t;
    if (node < N) row_start[node] = base + pref;
    __syncthreads();
    cnts[t] = 0;
    __syncthreads();
    for (int i = base + t; i < endb; i += 256) {
        int2 r = ee[i];
        int dl = (r.x >> 17) & 255;
        int rkk = atomicAdd(&cnts[dl], 1);
        int slot = prefs[dl] + rkk;
        if (slot < BCAP) out[slot] = make_int2(r.x & 0x1FFFF, r.y);
    }
    __syncthreads();
    // normalize this node's weights
    {
        int s0 = prefs[t], c = cnts[t];
        float sw = 0.f;
        for (int k = 0; k < c; ++k) sw += __int_as_float(out[s0 + k].y);
        sw = sw < 1.f ? 1.f : sw;
        float inv = 1.f / sw;
        for (int k = 0; k < c; ++k) {
            float w = __int_as_float(out[s0 + k].y) * inv;
            out[s0 + k].y = (int)(unsigned)__half_as_ushort(__float2half(w));
        }
    }
    __syncthreads();
    for (int i = t; i < cnt; i += 256)
        ee4[base + i] = ((unsigned)out[i].x << 15) | ((unsigned)out[i].y >> 1);
}

// ---------------- gather-aggregate, feature-sliced, wide-load/deep-ILP ----------------
// blockIdx&7 = slice s (XCD-affine under round-robin dispatch; slice h = 3.2 MB < 4 MB L2).
// Wave = 2 nodes; lane = (node n2, edge slot e 0..15, row-half hf). One uint4 gather
// instruction fetches 64 edge-row-halves (1024 B); 16 edges in flight per node.
__global__ __launch_bounds__(256) void agg_kernel(const char* __restrict__ hxs,
                                                  const int* __restrict__ row_start,
                                                  const unsigned* __restrict__ ee4,
                                                  char* __restrict__ aggs, int N) {
    int s = blockIdx.x & 7;
    int cb = blockIdx.x >> 3;
    int t = threadIdx.x;
    int w = t >> 6, lane = t & 63;
    int n2 = lane >> 5;       // node within wave
    int e = (lane >> 1) & 15; // edge slot
    int hf = lane & 1;        // 16B row half
    int nd = cb * 8 + w * 2 + n2;
    size_t sN = (size_t)s * N;
    int rs = 0, re = 0;
    if (nd < N) {
        rs = row_start[nd];
        re = row_start[nd + 1];
    }
    __half2 a0 = u2h2(0), a1 = u2h2(0), a2 = u2h2(0), a3 = u2h2(0);
    int idx = rs + e;
    while (__any(idx < re)) {
        bool act = idx < re;
        unsigned rec = __builtin_nontemporal_load(ee4 + (act ? idx : rs));
        rec = act ? rec : 0u;  // w=0 for inactive lanes
        unsigned hw = (rec & 0x7FFFu) << 1;
        __half2 w2 = u2h2(hw | (hw << 16));
        unsigned srcv = rec >> 15;
        uint4 hv = *reinterpret_cast<const uint4*>(hxs + ((sN + srcv) << 5) + hf * 16);
        a0 = __hfma2(u2h2(hv.x), w2, a0);
        a1 = __hfma2(u2h2(hv.y), w2, a1);
        a2 = __hfma2(u2h2(hv.z), w2, a2);
        a3 = __hfma2(u2h2(hv.w), w2, a3);
        idx += 16;
    }
    // reduce across edge slots (offsets 2,4,8,16) within each node's 32-lane group
#pragma unroll
    for (int off = 2; off <= 16; off <<= 1) {
        a0 = __hadd2(a0, u2h2((unsigned)__shfl_xor((int)h22u(a0), off)));
        a1 = __hadd2(a1, u2h2((unsigned)__shfl_xor((int)h22u(a1), off)));
        a2 = __hadd2(a2, u2h2((unsigned)__shfl_xor((int)h22u(a2), off)));
        a3 = __hadd2(a3, u2h2((unsigned)__shfl_xor((int)h22u(a3), off)));
    }
    if (e == 0 && nd < N) {
        uint4 r = make_uint4(h22u(a0), h22u(a1), h22u(a2), h22u(a3));
        *reinterpret_cast<uint4*>(aggs + ((sN + nd) << 5) + hf * 16) = r;
    }
}

// ---------------- MFMA dual-GEMM + bias + relu + layernorm (f16, sliced A) ----------------
__global__ __launch_bounds__(256, 2) void gemm_ln_mfma(
    const char* __restrict__ aggs, const char* __restrict__ hxs,
    const float* __restrict__ Wn, const float* __restrict__ Wr,
    const float* __restrict__ br, const float* __restrict__ g,
    const float* __restrict__ b, unsigned short* __restrict__ hout,
    float* __restrict__ outf, int final_layer, int N) {
    __shared__ half8 Bfl[4096];  // 64 KB

    int t = threadIdx.x;
    int w = t >> 6, lane = t & 63;
    int Mbase = blockIdx.x * 256;

#pragma unroll
    for (int it = 0; it < 16; ++it) {
        int f = it * 4 + w;
        int kt = f >> 3, nb = f & 7;
        int n = nb * 16 + (lane & 15);
        int kk = (kt & 3) * 32 + (lane >> 4) * 8;
        const float* wp = ((kt < 4) ? Wn : Wr) + (size_t)n * H + kk;
        float4 wa = *reinterpret_cast<const float4*>(wp);
        float4 wb = *reinterpret_cast<const float4*>(wp + 4);
        half8 sv;
        sv[0] = (_Float16)wa.x; sv[1] = (_Float16)wa.y;
        sv[2] = (_Float16)wa.z; sv[3] = (_Float16)wa.w;
        sv[4] = (_Float16)wb.x; sv[5] = (_Float16)wb.y;
        sv[6] = (_Float16)wb.z; sv[7] = (_Float16)wb.w;
        Bfl[f * 64 + lane] = sv;
    }
    __syncthreads();

    int lrow = lane & 15, lk = lane >> 4;
    int lk1 = lk & 1, lkh = lk >> 1;
    size_t rowb[4];
#pragma unroll
    for (int mf = 0; mf < 4; ++mf) {
        int r = Mbase + w * 64 + mf * 16 + lrow;
        r = r < N ? r : N - 1;
        rowb[mf] = (size_t)r << 5;  // r*32 bytes within a slice
    }

    f32x4 acc[4][8];
#pragma unroll
    for (int mf = 0; mf < 4; ++mf)
#pragma unroll
        for (int nb = 0; nb < 8; ++nb) acc[mf][nb] = (f32x4){0.f, 0.f, 0.f, 0.f};

#pragma unroll
    for (int kt = 0; kt < 8; ++kt) {
        const char* base = (kt < 4) ? aggs : hxs;
        size_t soff = (((size_t)((kt & 3) * 2 + lkh)) * (size_t)N << 5) + (size_t)lk1 * 16;
        half8 bf[8];
#pragma unroll
        for (int nb = 0; nb < 8; ++nb) bf[nb] = Bfl[(kt * 8 + nb) * 64 + lane];
#pragma unroll
        for (int mf = 0; mf < 4; ++mf) {
            half8 av = *reinterpret_cast<const half8*>(base + soff + rowb[mf]);
#pragma unroll
            for (int nb = 0; nb < 8; ++nb)
                acc[mf][nb] = __builtin_amdgcn_mfma_f32_16x16x32_f16(av, bf[nb], acc[mf][nb], 0, 0, 0);
        }
    }

    int col0 = lane & 15, rq = lane >> 4;
    float bias[8], gg[8], bbv[8];
#pragma unroll
    for (int nb = 0; nb < 8; ++nb) {
        int cc = col0 + nb * 16;
        bias[nb] = br[cc];
        gg[nb] = g[cc];
        bbv[nb] = b[cc];
    }
#pragma unroll
    for (int mf = 0; mf < 4; ++mf) {
#pragma unroll
        for (int reg = 0; reg < 4; ++reg) {
            float v[8];
            float sacc = 0.f, q = 0.f;
#pragma unroll
            for (int nb = 0; nb < 8; ++nb) {
                float u = acc[mf][nb][reg] + bias[nb];
                u = fmaxf(u, 0.f);
                v[nb] = u;
                sacc += u;
                q = fmaf(u, u, q);
            }
#pragma unroll
            for (int off = 1; off < 16; off <<= 1) {
                sacc += __shfl_xor(sacc, off);
                q += __shfl_xor(q, off);
            }
            float mu = sacc * (1.f / 128.f);
            float var = q * (1.f / 128.f) - mu * mu;
            float inv = rsqrtf(var + EPS);
            int grow = Mbase + w * 64 + mf * 16 + rq * 4 + reg;
            if (grow < N) {
                if (final_layer) {
#pragma unroll
                    for (int nb = 0; nb < 8; ++nb)
                        outf[(size_t)grow * H + col0 + nb * 16] = (v[nb] - mu) * inv * gg[nb] + bbv[nb];
                } else {
#pragma unroll
                    for (int nb = 0; nb < 8; ++nb)
                        hout[(((size_t)nb * N + grow) << 4) + col0] =
                            __half_as_ushort(__float2half((v[nb] - mu) * inv * gg[nb] + bbv[nb]));
                }
            }
        }
    }
}

static inline size_t alignup(size_t x) { return (x + 255) & ~(size_t)255; }

extern "C" void kernel_launch(void* const* d_in, const int* in_sizes, int n_in,
                              void* d_out, int out_size, void* d_ws, size_t ws_size,
                              hipStream_t stream) {
    const float* x  = (const float*)d_in[0];
    const int*   ei = (const int*)d_in[1];
    const float* ew = (const float*)d_in[2];
    const float* Wn = (const float*)d_in[3];
    const float* Wr = (const float*)d_in[4];
    const float* br = (const float*)d_in[5];
    const float* g  = (const float*)d_in[6];
    const float* bb = (const float*)d_in[7];
    float* out = (float*)d_out;

    int N = in_sizes[0] / H;
    int E = in_sizes[2];
    const int* src = ei;
    const int* dst = ei + E;
    int NB = (N + 255) >> 8;

    // ws layout (bytes)
    char* ws = (char*)d_ws;
    size_t off = 0;
    int* ghist = (int*)(ws + off);         off = alignup(off + sizeof(int) * 512);
    int* bucket_base = (int*)(ws + off);   off = alignup(off + sizeof(int) * 513);
    int* cursor = (int*)(ws + off);        off = alignup(off + sizeof(int) * 512);
    int* row_start = (int*)(ws + off);     off = alignup(off + sizeof(int) * ((size_t)N + 1));
    int2* ee = (int2*)(ws + off);          off = alignup(off + sizeof(int2) * (size_t)E);
    unsigned* ee4 = (unsigned*)(ws + off); off = alignup(off + sizeof(unsigned) * (size_t)E);
    char* aggs = ws + off;                 off = alignup(off + 2ull * N * H);
    char* hxs  = ws + off;                 off = alignup(off + 2ull * N * H);

    int eblocks = (E + 8191) / 8192;

    // CSR build via bucketed counting sort (+ weight normalization, 4B records)
    hipMemsetAsync(ghist, 0, sizeof(int) * 512, stream);
    bhist_kernel<<<eblocks, 256, 0, stream>>>(dst, ghist, E, NB);
    bscan_kernel<<<1, 512, 0, stream>>>(ghist, bucket_base, cursor, row_start, NB, E, N);
    bucketize_kernel<<<eblocks, 1024, 0, stream>>>(src, dst, ew, cursor, ee, E, NB);
    bsort_kernel<<<NB, 256, 0, stream>>>(ee, bucket_base, row_start, ee4, N);

    // x -> f16 sliced ping buffer
    int cthreads = N * 16;
    convert_kernel<<<(cthreads + 255) / 256, 256, 0, stream>>>(x, hxs, N);

    int gblocks = (N + 255) / 256;
    int ablocks = 8 * ((N + 7) / 8);
    for (int l = 0; l < 3; ++l) {
        agg_kernel<<<ablocks, 256, 0, stream>>>(hxs, row_start, ee4, aggs, N);
        gemm_ln_mfma<<<gblocks, 256, 0, stream>>>(
            aggs, hxs,
            Wn + (size_t)l * H * H, Wr + (size_t)l * H * H, br + (size_t)l * H,
            g + (size_t)l * H, bb + (size_t)l * H,
            (unsigned short*)hxs, out, (l == 2) ? 1 : 0, N);
    }
}

// Round 9
// 306.533 us; speedup vs baseline: 2.7673x; 1.7619x over previous
//
#include <hip/hip_runtime.h>
#include <hip/hip_fp16.h>

#define H 128
#define EPS 1e-5f
#define BCAP 6144  // max edges per 256-node bucket (mean 4096)

typedef __attribute__((ext_vector_type(8))) _Float16 half8;
typedef __attribute__((ext_vector_type(4))) float f32x4;

__device__ inline __half2 u2h2(unsigned u) { return __builtin_bit_cast(__half2, u); }
__device__ inline unsigned h22u(__half2 h) { return __builtin_bit_cast(unsigned, h); }

// ---------------- x f32 -> f16 (row-major) ----------------
__global__ void convert_kernel(const float* __restrict__ x, unsigned* __restrict__ hx, int n4) {
    int i = blockIdx.x * 256 + threadIdx.x;
    if (i >= n4) return;
    float4 v = reinterpret_cast<const float4*>(x)[i];
    unsigned p0 = h22u(__floats2half2_rn(v.x, v.y));
    unsigned p1 = h22u(__floats2half2_rn(v.z, v.w));
    reinterpret_cast<uint2*>(hx)[i] = make_uint2(p0, p1);
}

// ---------------- CSR build: bucket histogram (bucket = dst>>8) ----------------
__global__ __launch_bounds__(256) void bhist_kernel(const int* __restrict__ dst,
                                                    int* __restrict__ ghist, int E, int NB) {
    __shared__ int hist[512];
    int t = threadIdx.x;
    for (int i = t; i < NB; i += 256) hist[i] = 0;
    __syncthreads();
    int base = blockIdx.x * 8192 + t;
#pragma unroll
    for (int k = 0; k < 32; ++k) {
        int e = base + k * 256;
        if (e < E) atomicAdd(&hist[dst[e] >> 8], 1);
    }
    __syncthreads();
    for (int i = t; i < NB; i += 256)
        if (hist[i]) atomicAdd(&ghist[i], hist[i]);
}

__global__ __launch_bounds__(512) void bscan_kernel(const int* __restrict__ ghist,
                                                    int* __restrict__ bucket_base,
                                                    int* __restrict__ cursor,
                                                    int* __restrict__ row_start,
                                                    int NB, int E, int N) {
    __shared__ int lds[512];
    int t = threadIdx.x;
    int v = (t < NB) ? ghist[t] : 0;
    lds[t] = v;
    __syncthreads();
    for (int off = 1; off < 512; off <<= 1) {
        int u = (t >= off) ? lds[t - off] : 0;
        __syncthreads();
        lds[t] += u;
        __syncthreads();
    }
    int excl = lds[t] - v;
    if (t < NB) {
        bucket_base[t] = excl;
        cursor[t] = excl;
    }
    if (t == 0) {
        bucket_base[NB] = E;
        row_start[N] = E;
    }
}

// ---------------- bucketize: group edges by bucket in LDS, flush coalesced ----------------
__global__ __launch_bounds__(1024) void bucketize_kernel(const int* __restrict__ src,
                                                         const int* __restrict__ dst,
                                                         const float* __restrict__ ew,
                                                         int* __restrict__ cursor,
                                                         int2* __restrict__ ee, int E, int NB) {
    __shared__ int hist[512];
    __shared__ int scn[512];
    __shared__ int gbase[512];
    __shared__ int2 stage[8192];
    int t = threadIdx.x;
    for (int i = t; i < NB; i += 1024) hist[i] = 0;
    __syncthreads();

    int e0 = blockIdx.x * 8192;
    int bb[8], rk[8], pk[8], wb[8];
#pragma unroll
    for (int k = 0; k < 8; ++k) {
        int e = e0 + t + k * 1024;
        if (e < E) {
            int s = src[e], d = dst[e];
            bb[k] = d >> 8;
            pk[k] = s | ((d & 255) << 17);
            wb[k] = __float_as_int(ew[e]);
            rk[k] = atomicAdd(&hist[bb[k]], 1);
        } else {
            bb[k] = -1;
        }
    }
    __syncthreads();
    if (t < 512) scn[t] = (t < NB) ? hist[t] : 0;
    __syncthreads();
    for (int off = 1; off < 512; off <<= 1) {
        int u = 0;
        if (t < 512 && t >= off) u = scn[t - off];
        __syncthreads();
        if (t < 512) scn[t] += u;
        __syncthreads();
    }
    for (int i = t; i < NB; i += 1024) {
        int c = hist[i];
        if (c > 0) gbase[i] = atomicAdd(&cursor[i], c);
    }
#pragma unroll
    for (int k = 0; k < 8; ++k) {
        if (bb[k] >= 0) {
            int start = scn[bb[k]] - hist[bb[k]];
            stage[start + rk[k]] = make_int2(pk[k], wb[k]);
        }
    }
    __syncthreads();
    int wv = t >> 6, ln = t & 63;
    for (int bk = wv; bk < NB; bk += 16) {
        int c = hist[bk];
        if (c == 0) continue;
        int s0 = scn[bk] - c;
        int gb = gbase[bk];
        for (int i = ln; i < c; i += 64) ee[gb + i] = stage[s0 + i];
    }
}

// ------ per-bucket counting sort + row_start + weight normalization -> 4B records ------
// rec = (src << 15) | (half_bits(wn) >> 1), wn = w / max(sum_w(dst),1)
__global__ __launch_bounds__(256) void bsort_kernel(const int2* __restrict__ ee,
                                                    const int* __restrict__ bucket_base,
                                                    int* __restrict__ row_start,
                                                    unsigned* __restrict__ ee4, int N) {
    __shared__ int cnts[256];
    __shared__ int scv[256];
    __shared__ int prefs[256];
    __shared__ int2 out[BCAP];
    int b = blockIdx.x;
    int base = bucket_base[b], endb = bucket_base[b + 1];
    int cnt = endb - base;
    int t = threadIdx.x;
    cnts[t] = 0;
    __syncthreads();
    for (int i = base + t; i < endb; i += 256) atomicAdd(&cnts[(ee[i].x >> 17) & 255], 1);
    __syncthreads();
    scv[t] = cnts[t];
    __syncthreads();
    for (int off = 1; off < 256; off <<= 1) {
        int u = (t >= off) ? scv[t - off] : 0;
        __syncthreads();
        scv[t] += u;
        __syncthreads();
    }
    int pref = scv[t] - cnts[t];  // exclusive
    prefs[t] = pref;
    int node = (b << 8) + t;
    if (node < N) row_start[node] = base + pref;
    __syncthreads();
    cnts[t] = 0;
    __syncthreads();
    for (int i = base + t; i < endb; i += 256) {
        int2 r = ee[i];
        int dl = (r.x >> 17) & 255;
        int rkk = atomicAdd(&cnts[dl], 1);
        int slot = prefs[dl] + rkk;
        if (slot < BCAP) out[slot] = make_int2(r.x & 0x1FFFF, r.y);
    }
    __syncthreads();
    // normalize this node's weights
    {
        int s0 = prefs[t], c = cnts[t];
        float sw = 0.f;
        for (int k = 0; k < c; ++k) sw += __int_as_float(out[s0 + k].y);
        sw = sw < 1.f ? 1.f : sw;
        float inv = 1.f / sw;
        for (int k = 0; k < c; ++k) {
            float w = __int_as_float(out[s0 + k].y) * inv;
            out[s0 + k].y = (int)(unsigned)__half_as_ushort(__float2half(w));
        }
    }
    __syncthreads();
    for (int i = t; i < cnt; i += 256)
        ee4[base + i] = ((unsigned)out[i].x << 15) | ((unsigned)out[i].y >> 1);
}

// ---------------- gather-aggregate (f16 h, 4B records, 16 edges in flight) ----------------
// 1 wave per node, 4 nodes/block. Quarter q (16 lanes x uint4) covers a 256B row;
// quarter handles edges i+q*4..i+q*4+3 via one aligned uint4 record load.
__global__ __launch_bounds__(256) void agg_kernel(const unsigned short* __restrict__ hx,
                                                  const int* __restrict__ row_start,
                                                  const unsigned* __restrict__ ee4,
                                                  unsigned short* __restrict__ aggb, int N) {
    int t = threadIdx.x;
    int node = blockIdx.x * 4 + (t >> 6);
    if (node >= N) return;
    int lane = t & 63, q = lane >> 4, jb = lane & 15;
    int rs = row_start[node], re = row_start[node + 1];
    __half2 h0 = u2h2(0), h1 = u2h2(0), h2 = u2h2(0), h3 = u2h2(0);
    for (int i = (rs & ~3); i < re; i += 16) {
        int rbase = i + q * 4;
        uint4 rv = *reinterpret_cast<const uint4*>(ee4 + rbase);  // 16B-aligned (rbase%4==0)
#pragma unroll
        for (int k = 0; k < 4; ++k) {
            unsigned rec = (k == 0) ? rv.x : (k == 1) ? rv.y : (k == 2) ? rv.z : rv.w;
            int idx = rbase + k;
            bool act = (idx >= rs) & (idx < re);
            rec = act ? rec : 0u;
            unsigned hw = (rec & 0x7FFFu) << 1;
            __half2 w2 = u2h2(hw | (hw << 16));
            unsigned srcv = rec >> 15;
            uint4 hv = *reinterpret_cast<const uint4*>(hx + (size_t)srcv * H + jb * 8);
            h0 = __hfma2(u2h2(hv.x), w2, h0);
            h1 = __hfma2(u2h2(hv.y), w2, h1);
            h2 = __hfma2(u2h2(hv.z), w2, h2);
            h3 = __hfma2(u2h2(hv.w), w2, h3);
        }
    }
    // reduce across the 4 quarters (disjoint edge subsets, same columns)
#pragma unroll
    for (int off = 16; off <= 32; off <<= 1) {
        h0 = __hadd2(h0, u2h2((unsigned)__shfl_xor((int)h22u(h0), off)));
        h1 = __hadd2(h1, u2h2((unsigned)__shfl_xor((int)h22u(h1), off)));
        h2 = __hadd2(h2, u2h2((unsigned)__shfl_xor((int)h22u(h2), off)));
        h3 = __hadd2(h3, u2h2((unsigned)__shfl_xor((int)h22u(h3), off)));
    }
    if (q == 0) {
        uint4 r = make_uint4(h22u(h0), h22u(h1), h22u(h2), h22u(h3));
        *reinterpret_cast<uint4*>(aggb + (size_t)node * H + jb * 8) = r;
    }
}

// ---------------- MFMA dual-GEMM + bias + relu + layernorm (f16, row-major) ----------------
__global__ __launch_bounds__(256, 2) void gemm_ln_mfma(
    const unsigned short* __restrict__ aggb, const unsigned short* __restrict__ hx,
    const float* __restrict__ Wn, const float* __restrict__ Wr,
    const float* __restrict__ br, const float* __restrict__ g,
    const float* __restrict__ b, unsigned short* __restrict__ hout,
    float* __restrict__ outf, int final_layer, int N) {
    __shared__ half8 Bfl[4096];  // 64 KB: (kt 0..7)*(nb 0..7) fragments, 64 lanes x 16B

    int t = threadIdx.x;
    int w = t >> 6, lane = t & 63;
    int Mbase = blockIdx.x * 256;

#pragma unroll
    for (int it = 0; it < 16; ++it) {
        int f = it * 4 + w;
        int kt = f >> 3, nb = f & 7;
        int n = nb * 16 + (lane & 15);
        int kk = (kt & 3) * 32 + (lane >> 4) * 8;
        const float* wp = ((kt < 4) ? Wn : Wr) + (size_t)n * H + kk;
        float4 wa = *reinterpret_cast<const float4*>(wp);
        float4 wb = *reinterpret_cast<const float4*>(wp + 4);
        half8 sv;
        sv[0] = (_Float16)wa.x; sv[1] = (_Float16)wa.y;
        sv[2] = (_Float16)wa.z; sv[3] = (_Float16)wa.w;
        sv[4] = (_Float16)wb.x; sv[5] = (_Float16)wb.y;
        sv[6] = (_Float16)wb.z; sv[7] = (_Float16)wb.w;
        Bfl[f * 64 + lane] = sv;
    }
    __syncthreads();

    int lrow = lane & 15, lk = lane >> 4;
    const char* aggp = (const char*)aggb;
    const char* hp = (const char*)hx;
    size_t rb[4];
#pragma unroll
    for (int mf = 0; mf < 4; ++mf) {
        int r = Mbase + w * 64 + mf * 16 + lrow;
        r = r < N ? r : N - 1;
        rb[mf] = (size_t)r * 256;
    }

    f32x4 acc[4][8];
#pragma unroll
    for (int mf = 0; mf < 4; ++mf)
#pragma unroll
        for (int nb = 0; nb < 8; ++nb) acc[mf][nb] = (f32x4){0.f, 0.f, 0.f, 0.f};

#pragma unroll
    for (int kt = 0; kt < 8; ++kt) {
        const char* base = (kt < 4) ? aggp : hp;
        int off = (kt & 3) * 64 + lk * 16;
        half8 bf[8];
#pragma unroll
        for (int nb = 0; nb < 8; ++nb) bf[nb] = Bfl[(kt * 8 + nb) * 64 + lane];
#pragma unroll
        for (int mf = 0; mf < 4; ++mf) {
            half8 av = *reinterpret_cast<const half8*>(base + rb[mf] + off);
#pragma unroll
            for (int nb = 0; nb < 8; ++nb)
                acc[mf][nb] = __builtin_amdgcn_mfma_f32_16x16x32_f16(av, bf[nb], acc[mf][nb], 0, 0, 0);
        }
    }

    int col0 = lane & 15, rq = lane >> 4;
    float bias[8], gg[8], bbv[8];
#pragma unroll
    for (int nb = 0; nb < 8; ++nb) {
        int c = col0 + nb * 16;
        bias[nb] = br[c];
        gg[nb] = g[c];
        bbv[nb] = b[c];
    }
#pragma unroll
    for (int mf = 0; mf < 4; ++mf) {
#pragma unroll
        for (int reg = 0; reg < 4; ++reg) {
            float v[8];
            float s = 0.f, qq = 0.f;
#pragma unroll
            for (int nb = 0; nb < 8; ++nb) {
                float u = acc[mf][nb][reg] + bias[nb];
                u = fmaxf(u, 0.f);
                v[nb] = u;
                s += u;
                qq = fmaf(u, u, qq);
            }
#pragma unroll
            for (int off = 1; off < 16; off <<= 1) {
                s += __shfl_xor(s, off);
                qq += __shfl_xor(qq, off);
            }
            float mu = s * (1.f / 128.f);
            float var = qq * (1.f / 128.f) - mu * mu;
            float inv = rsqrtf(var + EPS);
            int grow = Mbase + w * 64 + mf * 16 + rq * 4 + reg;
            if (grow < N) {
                if (final_layer) {
#pragma unroll
                    for (int nb = 0; nb < 8; ++nb)
                        outf[(size_t)grow * H + col0 + nb * 16] = (v[nb] - mu) * inv * gg[nb] + bbv[nb];
                } else {
#pragma unroll
                    for (int nb = 0; nb < 8; ++nb)
                        hout[(size_t)grow * H + col0 + nb * 16] =
                            __half_as_ushort(__float2half((v[nb] - mu) * inv * gg[nb] + bbv[nb]));
                }
            }
        }
    }
}

static inline size_t alignup(size_t x) { return (x + 255) & ~(size_t)255; }

extern "C" void kernel_launch(void* const* d_in, const int* in_sizes, int n_in,
                              void* d_out, int out_size, void* d_ws, size_t ws_size,
                              hipStream_t stream) {
    const float* x  = (const float*)d_in[0];
    const int*   ei = (const int*)d_in[1];
    const float* ew = (const float*)d_in[2];
    const float* Wn = (const float*)d_in[3];
    const float* Wr = (const float*)d_in[4];
    const float* br = (const float*)d_in[5];
    const float* g  = (const float*)d_in[6];
    const float* bb = (const float*)d_in[7];
    float* out = (float*)d_out;

    int N = in_sizes[0] / H;
    int E = in_sizes[2];
    const int* src = ei;
    const int* dst = ei + E;
    int NB = (N + 255) >> 8;

    // ws layout (bytes)
    char* ws = (char*)d_ws;
    size_t off = 0;
    int* ghist = (int*)(ws + off);         off = alignup(off + sizeof(int) * 512);
    int* bucket_base = (int*)(ws + off);   off = alignup(off + sizeof(int) * 513);
    int* cursor = (int*)(ws + off);        off = alignup(off + sizeof(int) * 512);
    int* row_start = (int*)(ws + off);     off = alignup(off + sizeof(int) * ((size_t)N + 1));
    int2* ee = (int2*)(ws + off);          off = alignup(off + sizeof(int2) * (size_t)E);
    unsigned* ee4 = (unsigned*)(ws + off); off = alignup(off + sizeof(unsigned) * (size_t)E + 64);
    unsigned short* aggb = (unsigned short*)(ws + off); off = alignup(off + 2ull * N * H);
    unsigned short* hx = (unsigned short*)(ws + off);   off = alignup(off + 2ull * N * H);

    int eblocks = (E + 8191) / 8192;

    // CSR build via bucketed counting sort (+ weight normalization, 4B records)
    hipMemsetAsync(ghist, 0, sizeof(int) * 512, stream);
    bhist_kernel<<<eblocks, 256, 0, stream>>>(dst, ghist, E, NB);
    bscan_kernel<<<1, 512, 0, stream>>>(ghist, bucket_base, cursor, row_start, NB, E, N);
    bucketize_kernel<<<eblocks, 1024, 0, stream>>>(src, dst, ew, cursor, ee, E, NB);
    bsort_kernel<<<NB, 256, 0, stream>>>(ee, bucket_base, row_start, ee4, N);

    // x -> f16 ping buffer (row-major)
    int n4 = N * H / 4;
    convert_kernel<<<(n4 + 255) / 256, 256, 0, stream>>>(x, (unsigned*)hx, n4);

    int gblocks = (N + 255) / 256;
    for (int l = 0; l < 3; ++l) {
        agg_kernel<<<(N + 3) / 4, 256, 0, stream>>>(hx, row_start, ee4, aggb, N);
        gemm_ln_mfma<<<gblocks, 256, 0, stream>>>(
            aggb, hx,
            Wn + (size_t)l * H * H, Wr + (size_t)l * H * H, br + (size_t)l * H,
            g + (size_t)l * H, bb + (size_t)l * H,
            hx, out, (l == 2) ? 1 : 0, N);
    }
}